// Round 1
// baseline (107.515 us; speedup 1.0000x reference)
//
#include <hip/hip_runtime.h>

#define N_FEAT 128

// ws layout (floats):
// [0:192)    nm0[g*3+m] = mean(pf0)/std(pf0)
// [192:384)  is0[g*3+m] = 1/std(pf0)
// [384:576)  nm1
// [576:768)  is1
// [768:960)  C2[g*3+m]  = (logw - ln s0 - ln s1 - ln 2pi) * log2(e)
// ints at float-offset 960: pf0[64], pf1[64]

__global__ void spn_precompute(const float* __restrict__ means,
                               const float* __restrict__ stds,
                               const float* __restrict__ sumw,
                               const int* __restrict__ perm,
                               float* __restrict__ ws) {
    const float LOG2PI = 1.8378770664093453f;  // ln(2*pi)
    const float LOG2E  = 1.4426950408889634f;
    int g = threadIdx.x;
    if (g >= 64) return;
    int p0 = perm[2 * g], p1 = perm[2 * g + 1];
    int* pf = (int*)(ws + 960);
    pf[g] = p0;
    pf[64 + g] = p1;
    // log_softmax over sum_weights[g][0..2]
    float w0 = sumw[g * 3 + 0], w1 = sumw[g * 3 + 1], w2 = sumw[g * 3 + 2];
    float mx = fmaxf(w0, fmaxf(w1, w2));
    float lse = mx + logf(expf(w0 - mx) + expf(w1 - mx) + expf(w2 - mx));
    for (int m = 0; m < 3; ++m) {
        float s0 = stds[p0 * 3 + m], mu0 = means[p0 * 3 + m];
        float s1 = stds[p1 * 3 + m], mu1 = means[p1 * 3 + m];
        float i0 = 1.0f / s0, i1 = 1.0f / s1;
        float lw = sumw[g * 3 + m] - lse;
        ws[g * 3 + m]        = mu0 * i0;
        ws[192 + g * 3 + m]  = i0;
        ws[384 + g * 3 + m]  = mu1 * i1;
        ws[576 + g * 3 + m]  = i1;
        ws[768 + g * 3 + m]  = (lw - logf(s0) - logf(s1) - LOG2PI) * LOG2E;
    }
}

__global__ __launch_bounds__(256)
void spn_main(const float* __restrict__ x,
              const float* __restrict__ ws,
              float* __restrict__ out, int n) {
    const float NHALF_LOG2E = -0.7213475204444817f;  // -0.5*log2(e)
    const float LN2 = 0.6931471805599453f;

    const int lane   = threadIdx.x & 63;
    const int wave   = (blockIdx.x * blockDim.x + threadIdx.x) >> 6;
    const int nwaves = (gridDim.x * blockDim.x) >> 6;

    const int* pf = (const int*)(ws + 960);
    const int p0 = pf[lane];
    const int p1 = pf[64 + lane];
    float nm0[3], is0[3], nm1[3], is1[3], C2[3];
#pragma unroll
    for (int m = 0; m < 3; ++m) {
        nm0[m] = ws[lane * 3 + m];
        is0[m] = ws[192 + lane * 3 + m];
        nm1[m] = ws[384 + lane * 3 + m];
        is1[m] = ws[576 + lane * 3 + m];
        C2[m]  = ws[768 + lane * 3 + m];
    }

    int rpw  = (n + nwaves - 1) / nwaves;
    int row0 = wave * rpw;
    int row1 = row0 + rpw;
    if (row1 > n) row1 = n;

    for (int row = row0; row < row1; ++row) {
        const float* xr = x + (size_t)row * N_FEAT;
        float a = xr[p0];
        float b = xr[p1];
        float v0, v1, v2;
        {
            float z0 = fmaf(a, is0[0], -nm0[0]);
            float z1 = fmaf(b, is1[0], -nm1[0]);
            v0 = fmaf(z0 * z0, NHALF_LOG2E, C2[0]);
            v0 = fmaf(z1 * z1, NHALF_LOG2E, v0);
        }
        {
            float z0 = fmaf(a, is0[1], -nm0[1]);
            float z1 = fmaf(b, is1[1], -nm1[1]);
            v1 = fmaf(z0 * z0, NHALF_LOG2E, C2[1]);
            v1 = fmaf(z1 * z1, NHALF_LOG2E, v1);
        }
        {
            float z0 = fmaf(a, is0[2], -nm0[2]);
            float z1 = fmaf(b, is1[2], -nm1[2]);
            v2 = fmaf(z0 * z0, NHALF_LOG2E, C2[2]);
            v2 = fmaf(z1 * z1, NHALF_LOG2E, v2);
        }
        float mx = fmaxf(v0, fmaxf(v1, v2));
        float s = __builtin_amdgcn_exp2f(v0 - mx)
                + __builtin_amdgcn_exp2f(v1 - mx)
                + __builtin_amdgcn_exp2f(v2 - mx);
        float r = mx + __builtin_amdgcn_logf(s);  // v_log_f32 = log2
        // wave-wide sum over the 64 groups
#pragma unroll
        for (int off = 32; off >= 1; off >>= 1)
            r += __shfl_xor(r, off, 64);
        if (lane == 0) out[row] = r * LN2;
    }
}

extern "C" void kernel_launch(void* const* d_in, const int* in_sizes, int n_in,
                              void* d_out, int out_size, void* d_ws, size_t ws_size,
                              hipStream_t stream) {
    const float* x     = (const float*)d_in[0];
    const float* means = (const float*)d_in[1];
    const float* stds  = (const float*)d_in[2];
    const float* sumw  = (const float*)d_in[3];
    const int*   perm  = (const int*)d_in[4];
    float* ws  = (float*)d_ws;
    float* out = (float*)d_out;
    int n = in_sizes[0] / N_FEAT;  // 131072 rows

    hipLaunchKernelGGL(spn_precompute, dim3(1), dim3(64), 0, stream,
                       means, stds, sumw, perm, ws);
    hipLaunchKernelGGL(spn_main, dim3(2048), dim3(256), 0, stream,
                       x, ws, out, n);
}

// Round 2
// 102.618 us; speedup vs baseline: 1.0477x; 1.0477x over previous
//
#include <hip/hip_runtime.h>

#define N_FEAT 128
#define ROWS   32      // rows per LDS tile
#define TPB    256     // 4 waves; each wave computes 8 rows of the tile

__global__ __launch_bounds__(TPB)
void spn_fused(const float* __restrict__ x,
               const float* __restrict__ means,
               const float* __restrict__ stds,
               const float* __restrict__ sumw,
               const int* __restrict__ perm,
               float* __restrict__ out, int n) {
    __shared__ float sx[ROWS * N_FEAT];                    // 16 KB row tile
    __shared__ float snm0[192], sis0[192], snm1[192], sis1[192], sC2[192];
    __shared__ int   sp0[64], sp1[64];

    const float NHALF_LOG2E = -0.7213475204444817f;        // -0.5*log2(e)
    const float LN2 = 0.6931471805599453f;

    const int tid  = threadIdx.x;
    const int lane = tid & 63;
    const int wv   = tid >> 6;

    // ---- per-block param fold (threads 0..63, one group each) ----
    if (tid < 64) {
        const float LOG2PI_ = 1.8378770664093453f;         // ln(2*pi)
        const float LOG2E   = 1.4426950408889634f;
        const int g  = tid;
        const int p0 = perm[2 * g], p1 = perm[2 * g + 1];
        sp0[g] = p0; sp1[g] = p1;
        float w0 = sumw[g * 3 + 0], w1 = sumw[g * 3 + 1], w2 = sumw[g * 3 + 2];
        float mx  = fmaxf(w0, fmaxf(w1, w2));
        float lse = mx + logf(expf(w0 - mx) + expf(w1 - mx) + expf(w2 - mx));
#pragma unroll
        for (int m = 0; m < 3; ++m) {
            float s0 = stds[p0 * 3 + m], mu0 = means[p0 * 3 + m];
            float s1 = stds[p1 * 3 + m], mu1 = means[p1 * 3 + m];
            float i0 = 1.0f / s0, i1 = 1.0f / s1;
            float lw = sumw[g * 3 + m] - lse;
            snm0[g * 3 + m] = mu0 * i0;
            sis0[g * 3 + m] = i0;
            snm1[g * 3 + m] = mu1 * i1;
            sis1[g * 3 + m] = i1;
            sC2[g * 3 + m]  = (lw - logf(s0) - logf(s1) - LOG2PI_) * LOG2E;
        }
    }
    __syncthreads();

    // ---- per-lane loop-invariant registers ----
    const int p0 = sp0[lane];
    const int p1 = sp1[lane];
    float nm0[3], is0[3], nm1[3], is1[3], C2[3];
#pragma unroll
    for (int m = 0; m < 3; ++m) {
        nm0[m] = snm0[lane * 3 + m];
        is0[m] = sis0[lane * 3 + m];
        nm1[m] = snm1[lane * 3 + m];
        is1[m] = sis1[lane * 3 + m];
        C2[m]  = sC2[lane * 3 + m];
    }

    const int ntiles = n / ROWS;   // n = 131072 -> 4096 full tiles
    for (int tile = blockIdx.x; tile < ntiles; tile += gridDim.x) {
        const int rowbase = tile * ROWS;
        __syncthreads();           // protect sx from previous iteration's readers

        // coalesced float4 stage: 32x128 floats = 1024 float4, 4 per thread
        const float4* xv = (const float4*)(x + (size_t)rowbase * N_FEAT);
        float4* sv = (float4*)sx;
#pragma unroll
        for (int it = 0; it < 4; ++it)
            sv[it * TPB + tid] = xv[it * TPB + tid];
        __syncthreads();

        // ---- compute 8 rows per wave, fully unrolled for ILP ----
        float res[8];
#pragma unroll
        for (int r = 0; r < 8; ++r) {
            const float* xr = sx + (wv * 8 + r) * N_FEAT;
            const float a = xr[p0];
            const float b = xr[p1];
            float v0, v1, v2;
            {
                float z0 = fmaf(a, is0[0], -nm0[0]);
                float z1 = fmaf(b, is1[0], -nm1[0]);
                v0 = fmaf(z0 * z0, NHALF_LOG2E, C2[0]);
                v0 = fmaf(z1 * z1, NHALF_LOG2E, v0);
            }
            {
                float z0 = fmaf(a, is0[1], -nm0[1]);
                float z1 = fmaf(b, is1[1], -nm1[1]);
                v1 = fmaf(z0 * z0, NHALF_LOG2E, C2[1]);
                v1 = fmaf(z1 * z1, NHALF_LOG2E, v1);
            }
            {
                float z0 = fmaf(a, is0[2], -nm0[2]);
                float z1 = fmaf(b, is1[2], -nm1[2]);
                v2 = fmaf(z0 * z0, NHALF_LOG2E, C2[2]);
                v2 = fmaf(z1 * z1, NHALF_LOG2E, v2);
            }
            float mx = fmaxf(v0, fmaxf(v1, v2));
            float s = __builtin_amdgcn_exp2f(v0 - mx)
                    + __builtin_amdgcn_exp2f(v1 - mx)
                    + __builtin_amdgcn_exp2f(v2 - mx);
            res[r] = mx + __builtin_amdgcn_logf(s);   // v_log_f32 = log2
        }

        // 8 independent butterfly chains (ILP hides ds latency)
#pragma unroll
        for (int off = 32; off >= 1; off >>= 1) {
#pragma unroll
            for (int r = 0; r < 8; ++r)
                res[r] += __shfl_xor(res[r], off, 64);
        }

        if (lane == 0) {
#pragma unroll
            for (int r = 0; r < 8; ++r)
                out[rowbase + wv * 8 + r] = res[r] * LN2;
        }
    }
}

extern "C" void kernel_launch(void* const* d_in, const int* in_sizes, int n_in,
                              void* d_out, int out_size, void* d_ws, size_t ws_size,
                              hipStream_t stream) {
    const float* x     = (const float*)d_in[0];
    const float* means = (const float*)d_in[1];
    const float* stds  = (const float*)d_in[2];
    const float* sumw  = (const float*)d_in[3];
    const int*   perm  = (const int*)d_in[4];
    float* out = (float*)d_out;
    int n = in_sizes[0] / N_FEAT;  // 131072 rows

    hipLaunchKernelGGL(spn_fused, dim3(1024), dim3(TPB), 0, stream,
                       x, means, stds, sumw, perm, out, n);
}